// Round 8
// baseline (951.856 us; speedup 1.0000x reference)
//
#include <hip/hip_runtime.h>
#include <hip/hip_bf16.h>

#define T_DIM 512
#define B_DIM 16
#define D_DIM 1024
#define N_DIM 512

// c-fold: store S' = C*S so the exp2 argument is a single fma.
// C = 2*log2(e); tanh via exp2: tanh(x) = 1 - 2/(exp2(C*x)+1)
#define C_FOLD  2.885390082f
#define INV_C   0.3465735903f

typedef short s16x8 __attribute__((ext_vector_type(8)));
typedef float f32x4 __attribute__((ext_vector_type(4)));

__device__ __forceinline__ unsigned short f2bf(float f) {
    unsigned u = __float_as_uint(f);
    unsigned r = (u + 0x7fffu + ((u >> 16) & 1u)) >> 16;
    return (unsigned short)r;
}

template <int CTRL, int RMASK>
__device__ __forceinline__ float dpp_add(float x) {
    return x + __int_as_float(__builtin_amdgcn_update_dpp(
        0, __float_as_int(x), CTRL, RMASK, 0xf, true));
}

// classic GCN 64-lane sum: after this, lane 63 holds the wave total.
// row_shr:1/2/4/8 (per-16 row sums accumulate toward lane 15 of each row),
// then row_bcast:15 (rows 1,3 += row 0/2 sums), row_bcast:31 (rows 2,3 +=
// lane31 cumulative). Masked-out lanes add old=0. Pure VALU, no DS ops.
__device__ __forceinline__ float wave_sum_lane63(float x) {
    x = dpp_add<0x111, 0xf>(x);   // row_shr:1
    x = dpp_add<0x112, 0xf>(x);   // row_shr:2
    x = dpp_add<0x114, 0xf>(x);   // row_shr:4
    x = dpp_add<0x118, 0xf>(x);   // row_shr:8
    x = dpp_add<0x142, 0xa>(x);   // row_bcast:15 -> rows 1,3
    x = dpp_add<0x143, 0xc>(x);   // row_bcast:31 -> rows 2,3
    return x;
}

// ---------------- projection GEMM: C[m,n] = sum_d x[m,d] * W[n,d] ----------
__global__ __launch_bounds__(256) void proj_gemm(
    const float* __restrict__ x,
    const float* __restrict__ Wk,
    const float* __restrict__ Wv,
    const float* __restrict__ Wq,
    float* __restrict__ kbuf, float* __restrict__ vbuf, float* __restrict__ qbuf)
{
    const float* W = (blockIdx.z == 0) ? Wk : (blockIdx.z == 1) ? Wv : Wq;
    float* out = (blockIdx.z == 0) ? kbuf : (blockIdx.z == 1) ? vbuf : qbuf;

    __shared__ __align__(16) unsigned short As[64 * 40];
    __shared__ __align__(16) unsigned short Bs[64 * 40];

    const int tid  = threadIdx.x;
    const int m0   = blockIdx.x * 64;
    const int n0   = blockIdx.y * 64;
    const int wave = tid >> 6;
    const int lane = tid & 63;
    const int l15  = lane & 15;
    const int quad = lane >> 4;

    const int srow = tid >> 2;
    const int scol = (tid & 3) * 8;

    f32x4 acc[4];
#pragma unroll
    for (int i = 0; i < 4; ++i) acc[i] = (f32x4)0.0f;

    for (int k0 = 0; k0 < D_DIM; k0 += 32) {
        __syncthreads();
        {
            const float* srcA = &x[(size_t)(m0 + srow) * D_DIM + k0 + scol];
            float4 a0 = *(const float4*)srcA;
            float4 a1 = *(const float4*)(srcA + 4);
            uint4 pa;
            pa.x = (unsigned)f2bf(a0.x) | ((unsigned)f2bf(a0.y) << 16);
            pa.y = (unsigned)f2bf(a0.z) | ((unsigned)f2bf(a0.w) << 16);
            pa.z = (unsigned)f2bf(a1.x) | ((unsigned)f2bf(a1.y) << 16);
            pa.w = (unsigned)f2bf(a1.z) | ((unsigned)f2bf(a1.w) << 16);
            *(uint4*)&As[srow * 40 + scol] = pa;

            const float* srcB = &W[(size_t)(n0 + srow) * D_DIM + k0 + scol];
            float4 b0 = *(const float4*)srcB;
            float4 b1 = *(const float4*)(srcB + 4);
            uint4 pb;
            pb.x = (unsigned)f2bf(b0.x) | ((unsigned)f2bf(b0.y) << 16);
            pb.y = (unsigned)f2bf(b0.z) | ((unsigned)f2bf(b0.w) << 16);
            pb.z = (unsigned)f2bf(b1.x) | ((unsigned)f2bf(b1.y) << 16);
            pb.w = (unsigned)f2bf(b1.z) | ((unsigned)f2bf(b1.w) << 16);
            *(uint4*)&Bs[srow * 40 + scol] = pb;
        }
        __syncthreads();
        s16x8 af = *(const s16x8*)&As[(wave * 16 + l15) * 40 + quad * 8];
#pragma unroll
        for (int nt = 0; nt < 4; ++nt) {
            s16x8 bf = *(const s16x8*)&Bs[(nt * 16 + l15) * 40 + quad * 8];
            acc[nt] = __builtin_amdgcn_mfma_f32_16x16x32_bf16(af, bf, acc[nt], 0, 0, 0);
        }
    }
#pragma unroll
    for (int nt = 0; nt < 4; ++nt) {
#pragma unroll
        for (int rg = 0; rg < 4; ++rg) {
            int row = m0 + wave * 16 + quad * 4 + rg;
            int col = n0 + nt * 16 + l15;
            out[(size_t)row * N_DIM + col] = acc[nt][rg];
        }
    }
}

// ---------------- k row-normalization (in place) ---------------------------
__global__ __launch_bounds__(256) void knorm(float* __restrict__ kbuf)
{
    const int wave = threadIdx.x >> 6;
    const int lane = threadIdx.x & 63;
    const int row  = blockIdx.x * 4 + wave;
    float* p = &kbuf[(size_t)row * N_DIM + lane * 8];
    float4 a = *(const float4*)p;
    float4 b = *(const float4*)(p + 4);
    float s = a.x*a.x + a.y*a.y + a.z*a.z + a.w*a.w
            + b.x*b.x + b.y*b.y + b.z*b.z + b.w*b.w;
#pragma unroll
    for (int m = 1; m < 64; m <<= 1) s += __shfl_xor(s, m, 64);
    float inv = 1.0f / (sqrtf(s) + 1e-6f);
    a.x *= inv; a.y *= inv; a.z *= inv; a.w *= inv;
    b.x *= inv; b.y *= inv; b.z *= inv; b.w *= inv;
    *(float4*)p = a;
    *(float4*)(p + 4) = b;
}

// ---------------- sequential scan ------------------------------------------
// grid(64, 16): x = 8-row chunk, y = batch. block 256 = 4 waves.
// Wave w owns rows {2w, 2w+1}; lane L owns cols [8L..8L+7] of both rows.
// Per-lane LDS traffic: 64 B/step (half of the 16-col layout) -> 4 blocks/CU
// at unchanged DS/CU, 4 waves/SIMD for latency hiding. Row reductions are
// 64-lane DPP chains (row_shr + row_bcast, no DS), result in lane 63;
// racc broadcast via readlane->SGPR. S' = C*S (c-fold). One barrier/step.
__global__ __launch_bounds__(256, 4) void scan_kernel(
    const float* __restrict__ kbuf, const float* __restrict__ vbuf,
    const float* __restrict__ qbuf, float* __restrict__ out)
{
    __shared__ __align__(16) float ks[2][512];
    __shared__ __align__(16) float qs[2][512];
    __shared__ float vs[2][8];

    const int tid  = threadIdx.x;
    const int w    = tid >> 6;        // wave 0..3
    const int L    = tid & 63;
    const int b    = blockIdx.y;
    const int i0   = blockIdx.x * 8;
    const int row0 = 2 * w;           // local rows 2w, 2w+1
    const int c0   = 8 * L;           // col base

    float S0[8], S1[8];               // S' = C*S for rows row0, row0+1
#pragma unroll
    for (int u = 0; u < 8; ++u) { S0[u] = 0.0f; S1[u] = 0.0f; }

    float2 pk, pq; float pv = 0.0f;
    {   // stage t=0 into buf0; prefetch t=1 into regs
        const size_t o0 = (size_t)b * N_DIM;
        pk = *(const float2*)&kbuf[o0 + 2 * tid];
        pq = *(const float2*)&qbuf[o0 + 2 * tid];
        if (tid < 8) pv = vbuf[o0 + i0 + tid];
        *(float2*)&ks[0][2 * tid] = pk;
        *(float2*)&qs[0][2 * tid] = pq;
        if (tid < 8) vs[0][tid] = pv;
        const size_t o1 = (size_t)(B_DIM + b) * N_DIM;
        pk = *(const float2*)&kbuf[o1 + 2 * tid];
        pq = *(const float2*)&qbuf[o1 + 2 * tid];
        if (tid < 8) pv = vbuf[o1 + i0 + tid];
    }
    __syncthreads();

    for (int t = 0; t < T_DIM; ++t) {
        const int cb = t & 1, nb = cb ^ 1;
        const size_t ofs = ((size_t)t * B_DIM + b) * N_DIM;

        // stage t+1 (already in regs) into the other buffer
        if (t + 1 < T_DIM) {
            *(float2*)&ks[nb][2 * tid] = pk;
            *(float2*)&qs[nb][2 * tid] = pq;
            if (tid < 8) vs[nb][tid] = pv;
        }
        // issue global prefetch for t+2
        if (t + 2 < T_DIM) {
            const size_t o2 = ((size_t)(t + 2) * B_DIM + b) * N_DIM;
            pk = *(const float2*)&kbuf[o2 + 2 * tid];
            pq = *(const float2*)&qbuf[o2 + 2 * tid];
            if (tid < 8) pv = vbuf[o2 + i0 + tid];
        }

        float kk[8], qq[8];
        {
            f32x4 k0v = *(const f32x4*)&ks[cb][c0];
            f32x4 k1v = *(const f32x4*)&ks[cb][c0 + 4];
            f32x4 q0v = *(const f32x4*)&qs[cb][c0];
            f32x4 q1v = *(const f32x4*)&qs[cb][c0 + 4];
#pragma unroll
            for (int u = 0; u < 4; ++u) {
                kk[u] = k0v[u]; kk[u + 4] = k1v[u];
                qq[u] = q0v[u]; qq[u + 4] = q1v[u];
            }
        }
        const float v0 = vs[cb][row0];
        const float v1 = vs[cb][row0 + 1];

        // racc' = sum_j S'_ij k_j  (2 partial chains per row for ILP)
        float a0 = 0.f, a1 = 0.f, b0 = 0.f, b1 = 0.f;
#pragma unroll
        for (int u = 0; u < 4; ++u) {
            a0 = __builtin_fmaf(S0[u],     kk[u],     a0);
            a1 = __builtin_fmaf(S0[u + 4], kk[u + 4], a1);
            b0 = __builtin_fmaf(S1[u],     kk[u],     b0);
            b1 = __builtin_fmaf(S1[u + 4], kk[u + 4], b1);
        }
        float red0 = wave_sum_lane63(a0 + a1);
        float red1 = wave_sum_lane63(b0 + b1);
        const float racc0 = __int_as_float(__builtin_amdgcn_readlane(__float_as_int(red0), 63));
        const float racc1 = __int_as_float(__builtin_amdgcn_readlane(__float_as_int(red1), 63));

        // dp' = C*v - racc'
        const float dp0 = __builtin_fmaf(C_FOLD, v0, -racc0);
        const float dp1 = __builtin_fmaf(C_FOLD, v1, -racc1);

        // S'_new = C - 2C*rcp(exp2(S' + dp'*k)+1);  sq' += S'_new * q
        float s0a = 0.f, s0b = 0.f, s1a = 0.f, s1b = 0.f;
#pragma unroll
        for (int u = 0; u < 8; ++u) {
            float g0 = __builtin_fmaf(dp0, kk[u], S0[u]);
            float g1 = __builtin_fmaf(dp1, kk[u], S1[u]);
            float e0 = __builtin_amdgcn_exp2f(g0) + 1.0f;
            float e1 = __builtin_amdgcn_exp2f(g1) + 1.0f;
            float n0 = __builtin_fmaf(-2.0f * C_FOLD, __builtin_amdgcn_rcpf(e0), C_FOLD);
            float n1 = __builtin_fmaf(-2.0f * C_FOLD, __builtin_amdgcn_rcpf(e1), C_FOLD);
            S0[u] = n0; S1[u] = n1;
            if (u & 1) { s0b = __builtin_fmaf(n0, qq[u], s0b); s1b = __builtin_fmaf(n1, qq[u], s1b); }
            else       { s0a = __builtin_fmaf(n0, qq[u], s0a); s1a = __builtin_fmaf(n1, qq[u], s1a); }
        }
        float sq0 = wave_sum_lane63(s0a + s0b);
        float sq1 = wave_sum_lane63(s1a + s1b);

        if (L == 63) {
            float t0 = sq0 * INV_C, t1 = sq1 * INV_C;
            float g0 = __builtin_amdgcn_rcpf(1.0f + __builtin_amdgcn_exp2f(-t0 * 1.44269504f));
            float g1 = __builtin_amdgcn_rcpf(1.0f + __builtin_amdgcn_exp2f(-t1 * 1.44269504f));
            float2 o2; o2.x = t0 * t0 * g0; o2.y = t1 * t1 * g1;
            *(float2*)&out[ofs + i0 + row0] = o2;
        }
        __syncthreads();
    }

    // S_final (true scale) -> d_out[T*B*N + ((b*N + i)*N + col)]
    const size_t base = (size_t)T_DIM * B_DIM * N_DIM;
    const size_t so0 = base + ((size_t)b * N_DIM + i0 + row0) * N_DIM + c0;
    const size_t so1 = so0 + N_DIM;
    float4 w0, w1;
    w0.x = S0[0] * INV_C; w0.y = S0[1] * INV_C; w0.z = S0[2] * INV_C; w0.w = S0[3] * INV_C;
    *(float4*)&out[so0] = w0;
    w0.x = S0[4] * INV_C; w0.y = S0[5] * INV_C; w0.z = S0[6] * INV_C; w0.w = S0[7] * INV_C;
    *(float4*)&out[so0 + 4] = w0;
    w1.x = S1[0] * INV_C; w1.y = S1[1] * INV_C; w1.z = S1[2] * INV_C; w1.w = S1[3] * INV_C;
    *(float4*)&out[so1] = w1;
    w1.x = S1[4] * INV_C; w1.y = S1[5] * INV_C; w1.z = S1[6] * INV_C; w1.w = S1[7] * INV_C;
    *(float4*)&out[so1 + 4] = w1;
}

extern "C" void kernel_launch(void* const* d_in, const int* in_sizes, int n_in,
                              void* d_out, int out_size, void* d_ws, size_t ws_size,
                              hipStream_t stream) {
    const float* x  = (const float*)d_in[0];
    const float* Wk = (const float*)d_in[1];
    const float* Wv = (const float*)d_in[2];
    const float* Wq = (const float*)d_in[3];
    float* outp = (float*)d_out;

    const size_t MN = (size_t)T_DIM * B_DIM * N_DIM;
    float* kbuf = (float*)d_ws;
    float* vbuf = kbuf + MN;
    float* qbuf = vbuf + MN;

    proj_gemm<<<dim3(128, 8, 3), 256, 0, stream>>>(x, Wk, Wv, Wq, kbuf, vbuf, qbuf);
    knorm<<<2048, 256, 0, stream>>>(kbuf);
    scan_kernel<<<dim3(64, 16), 256, 0, stream>>>(kbuf, vbuf, qbuf, outp);
}

// Round 9
// 919.054 us; speedup vs baseline: 1.0357x; 1.0357x over previous
//
#include <hip/hip_runtime.h>
#include <hip/hip_bf16.h>

#define T_DIM 512
#define B_DIM 16
#define D_DIM 1024
#define N_DIM 512

// c-fold: store S' = C*S so the exp2 argument is a single fma.
// C = 2*log2(e); tanh via exp2: tanh(x) = 1 - 2/(exp2(C*x)+1)
#define C_FOLD  2.885390082f
#define INV_C   0.3465735903f

typedef short s16x8 __attribute__((ext_vector_type(8)));
typedef float f32x4 __attribute__((ext_vector_type(4)));

__device__ __forceinline__ unsigned short f2bf(float f) {
    unsigned u = __float_as_uint(f);
    unsigned r = (u + 0x7fffu + ((u >> 16) & 1u)) >> 16;
    return (unsigned short)r;
}

template <int CTRL>
__device__ __forceinline__ float dpp_add(float x) {
    return x + __int_as_float(__builtin_amdgcn_update_dpp(
        0, __float_as_int(x), CTRL, 0xf, 0xf, true));
}

// all-lane sum within each 16-lane group: xor1, xor2 (quad butterfly) then
// ror4, ror8 (rotations cover all 4 quads). Every lane ends with the full
// 16-lane total. Pure VALU, 4 dependent DPP adds. (Chain validated in R3.)
__device__ __forceinline__ float sum16_bcast(float x) {
    x = dpp_add<0xB1>(x);    // quad_perm [1,0,3,2]  (xor 1)
    x = dpp_add<0x4E>(x);    // quad_perm [2,3,0,1]  (xor 2)
    x = dpp_add<0x124>(x);   // row_ror:4
    x = dpp_add<0x128>(x);   // row_ror:8
    return x;
}

// ---------------- projection GEMM: C[m,n] = sum_d x[m,d] * W[n,d] ----------
// v output pre-scaled by C_FOLD (scan works in S' = C*S domain).
__global__ __launch_bounds__(256) void proj_gemm(
    const float* __restrict__ x,
    const float* __restrict__ Wk,
    const float* __restrict__ Wv,
    const float* __restrict__ Wq,
    float* __restrict__ kbuf, float* __restrict__ vbuf, float* __restrict__ qbuf)
{
    const float* W = (blockIdx.z == 0) ? Wk : (blockIdx.z == 1) ? Wv : Wq;
    float* out = (blockIdx.z == 0) ? kbuf : (blockIdx.z == 1) ? vbuf : qbuf;
    const float oscale = (blockIdx.z == 1) ? C_FOLD : 1.0f;

    __shared__ __align__(16) unsigned short As[64 * 40];
    __shared__ __align__(16) unsigned short Bs[64 * 40];

    const int tid  = threadIdx.x;
    const int m0   = blockIdx.x * 64;
    const int n0   = blockIdx.y * 64;
    const int wave = tid >> 6;
    const int lane = tid & 63;
    const int l15  = lane & 15;
    const int quad = lane >> 4;

    const int srow = tid >> 2;
    const int scol = (tid & 3) * 8;

    f32x4 acc[4];
#pragma unroll
    for (int i = 0; i < 4; ++i) acc[i] = (f32x4)0.0f;

    for (int k0 = 0; k0 < D_DIM; k0 += 32) {
        __syncthreads();
        {
            const float* srcA = &x[(size_t)(m0 + srow) * D_DIM + k0 + scol];
            float4 a0 = *(const float4*)srcA;
            float4 a1 = *(const float4*)(srcA + 4);
            uint4 pa;
            pa.x = (unsigned)f2bf(a0.x) | ((unsigned)f2bf(a0.y) << 16);
            pa.y = (unsigned)f2bf(a0.z) | ((unsigned)f2bf(a0.w) << 16);
            pa.z = (unsigned)f2bf(a1.x) | ((unsigned)f2bf(a1.y) << 16);
            pa.w = (unsigned)f2bf(a1.z) | ((unsigned)f2bf(a1.w) << 16);
            *(uint4*)&As[srow * 40 + scol] = pa;

            const float* srcB = &W[(size_t)(n0 + srow) * D_DIM + k0 + scol];
            float4 b0 = *(const float4*)srcB;
            float4 b1 = *(const float4*)(srcB + 4);
            uint4 pb;
            pb.x = (unsigned)f2bf(b0.x) | ((unsigned)f2bf(b0.y) << 16);
            pb.y = (unsigned)f2bf(b0.z) | ((unsigned)f2bf(b0.w) << 16);
            pb.z = (unsigned)f2bf(b1.x) | ((unsigned)f2bf(b1.y) << 16);
            pb.w = (unsigned)f2bf(b1.z) | ((unsigned)f2bf(b1.w) << 16);
            *(uint4*)&Bs[srow * 40 + scol] = pb;
        }
        __syncthreads();
        s16x8 af = *(const s16x8*)&As[(wave * 16 + l15) * 40 + quad * 8];
#pragma unroll
        for (int nt = 0; nt < 4; ++nt) {
            s16x8 bf = *(const s16x8*)&Bs[(nt * 16 + l15) * 40 + quad * 8];
            acc[nt] = __builtin_amdgcn_mfma_f32_16x16x32_bf16(af, bf, acc[nt], 0, 0, 0);
        }
    }
#pragma unroll
    for (int nt = 0; nt < 4; ++nt) {
#pragma unroll
        for (int rg = 0; rg < 4; ++rg) {
            int row = m0 + wave * 16 + quad * 4 + rg;
            int col = n0 + nt * 16 + l15;
            out[(size_t)row * N_DIM + col] = acc[nt][rg] * oscale;
        }
    }
}

// ---------------- k row-normalization (in place) ---------------------------
__global__ __launch_bounds__(256) void knorm(float* __restrict__ kbuf)
{
    const int wave = threadIdx.x >> 6;
    const int lane = threadIdx.x & 63;
    const int row  = blockIdx.x * 4 + wave;
    float* p = &kbuf[(size_t)row * N_DIM + lane * 8];
    float4 a = *(const float4*)p;
    float4 b = *(const float4*)(p + 4);
    float s = a.x*a.x + a.y*a.y + a.z*a.z + a.w*a.w
            + b.x*b.x + b.y*b.y + b.z*b.z + b.w*b.w;
#pragma unroll
    for (int m = 1; m < 64; m <<= 1) s += __shfl_xor(s, m, 64);
    float inv = 1.0f / (sqrtf(s) + 1e-6f);
    a.x *= inv; a.y *= inv; a.z *= inv; a.w *= inv;
    b.x *= inv; b.y *= inv; b.z *= inv; b.w *= inv;
    *(float4*)p = a;
    *(float4*)(p + 4) = b;
}

// ---------------- sequential scan ------------------------------------------
// grid(32, 16): x = 16-row chunk, y = batch. block 256 = 4 waves.
// Lane (w=tid>>6, g=(tid&63)>>4, c=tid&15) owns row 4w+g, cols [32c..32c+31]
// of S' (= C*S): 32 fp32 in regs. k/q double-buffered in LDS, 16 chunks of
// 32 cols at stride 33 words: every dword-phase of a 16-lane b128 read hits
// 16 distinct banks (conflict-free). Row reductions: 4 DPP adds per 16-lane
// group with full broadcast (no swizzle/readlane). sq reduction of step t is
// deferred into step t+1 (overlaps the racc chain); output write lags 1 step.
__global__ __launch_bounds__(256, 2) void scan_kernel(
    const float* __restrict__ kbuf, const float* __restrict__ vbuf,
    const float* __restrict__ qbuf, float* __restrict__ out)
{
    __shared__ __align__(16) float ks[2][528];
    __shared__ __align__(16) float qs[2][528];
    __shared__ float vs[2][16];

    const int tid = threadIdx.x;
    const int w   = tid >> 6;
    const int L   = tid & 63;
    const int g   = L >> 4;
    const int c   = L & 15;
    const int b   = blockIdx.y;
    const int i0  = blockIdx.x * 16;
    const int row = 4 * w + g;            // local row 0..15

    const int col2 = 2 * tid;             // staged cols {col2, col2+1}
    const int wA = 33 * (col2 >> 5) + (col2 & 31);
    const int rA = 33 * c;

    float S[32];
#pragma unroll
    for (int u = 0; u < 32; ++u) S[u] = 0.0f;

    float2 pk, pq; float pv = 0.0f;
    {   // stage t=0 into buf0; prefetch t=1 into regs
        const size_t o0 = (size_t)b * N_DIM;
        pk = *(const float2*)&kbuf[o0 + col2];
        pq = *(const float2*)&qbuf[o0 + col2];
        if (tid < 16) pv = vbuf[o0 + i0 + tid];
        *(float2*)&ks[0][wA] = pk;
        *(float2*)&qs[0][wA] = pq;
        if (tid < 16) vs[0][tid] = pv;
        const size_t o1 = (size_t)(B_DIM + b) * N_DIM;
        pk = *(const float2*)&kbuf[o1 + col2];
        pq = *(const float2*)&qbuf[o1 + col2];
        if (tid < 16) pv = vbuf[o1 + i0 + tid];
    }
    __syncthreads();

    float sqp = 0.0f;                      // deferred sq partial from step t-1

    for (int t = 0; t < T_DIM; ++t) {
        const int cb = t & 1, nb = cb ^ 1;
        const size_t ofs = ((size_t)t * B_DIM + b) * N_DIM;

        // stage t+1 (already in regs) into the other buffer
        if (t + 1 < T_DIM) {
            *(float2*)&ks[nb][wA] = pk;
            *(float2*)&qs[nb][wA] = pq;
            if (tid < 16) vs[nb][tid] = pv;
        }
        // issue global prefetch for t+2
        if (t + 2 < T_DIM) {
            const size_t o2 = ((size_t)(t + 2) * B_DIM + b) * N_DIM;
            pk = *(const float2*)&kbuf[o2 + col2];
            pq = *(const float2*)&qbuf[o2 + col2];
            if (tid < 16) pv = vbuf[o2 + i0 + tid];
        }

        f32x4 kk[8], qq[8];
#pragma unroll
        for (int u = 0; u < 8; ++u) {
            kk[u] = *(const f32x4*)&ks[cb][rA + 4 * u];
            qq[u] = *(const f32x4*)&qs[cb][rA + 4 * u];
        }
        const float vv = vs[cb][row];      // = C * v (pre-scaled in GEMM)

        // racc' = sum_j S'_ij k_j  (4 independent fma chains)
        float a0 = 0.f, a1 = 0.f, a2 = 0.f, a3 = 0.f;
#pragma unroll
        for (int u = 0; u < 8; ++u) {
            a0 = __builtin_fmaf(S[4*u    ], kk[u][0], a0);
            a1 = __builtin_fmaf(S[4*u + 1], kk[u][1], a1);
            a2 = __builtin_fmaf(S[4*u + 2], kk[u][2], a2);
            a3 = __builtin_fmaf(S[4*u + 3], kk[u][3], a3);
        }
        const float racc = sum16_bcast((a0 + a1) + (a2 + a3));

        // reduce PREVIOUS step's sq in parallel with the racc chain
        // (independent DPP chains interleave on the VALU)
        if (t > 0) {
            float sqt = sum16_bcast(sqp) * INV_C;
            if (c == 0) {
                float gg = __builtin_amdgcn_rcpf(
                    1.0f + __builtin_amdgcn_exp2f(-sqt * 1.44269504f));
                out[ofs - (size_t)B_DIM * N_DIM + i0 + row] = sqt * sqt * gg;
            }
        }

        const float dp = vv - racc;        // dp' = C*v - racc'

        // S'_new = C - 2C*rcp(exp2(S' + dp'*k)+1);  sq' += S'_new * q
        float s0 = 0.f, s1 = 0.f, s2 = 0.f, s3 = 0.f;
#pragma unroll
        for (int u = 0; u < 8; ++u) {
#pragma unroll
            for (int j = 0; j < 4; ++j) {
                const int idx = 4 * u + j;
                float arg = __builtin_fmaf(dp, kk[u][j], S[idx]);
                float e   = __builtin_amdgcn_exp2f(arg) + 1.0f;
                float sn  = __builtin_fmaf(-2.0f * C_FOLD,
                                           __builtin_amdgcn_rcpf(e), C_FOLD);
                S[idx] = sn;
                if      (j == 0) s0 = __builtin_fmaf(sn, qq[u][j], s0);
                else if (j == 1) s1 = __builtin_fmaf(sn, qq[u][j], s1);
                else if (j == 2) s2 = __builtin_fmaf(sn, qq[u][j], s2);
                else             s3 = __builtin_fmaf(sn, qq[u][j], s3);
            }
        }
        sqp = (s0 + s1) + (s2 + s3);

        __syncthreads();
    }

    // flush last step's output
    {
        const size_t ofsL = ((size_t)(T_DIM - 1) * B_DIM + b) * N_DIM;
        float sqt = sum16_bcast(sqp) * INV_C;
        if (c == 0) {
            float gg = __builtin_amdgcn_rcpf(
                1.0f + __builtin_amdgcn_exp2f(-sqt * 1.44269504f));
            out[ofsL + i0 + row] = sqt * sqt * gg;
        }
    }

    // S_final (true scale) -> d_out[T*B*N + ((b*N + i)*N + col)]
    const size_t so = (size_t)T_DIM * B_DIM * N_DIM
                    + ((size_t)b * N_DIM + i0 + row) * N_DIM + 32 * c;
#pragma unroll
    for (int u = 0; u < 8; ++u) {
        float4 w4;
        w4.x = S[4*u    ] * INV_C;
        w4.y = S[4*u + 1] * INV_C;
        w4.z = S[4*u + 2] * INV_C;
        w4.w = S[4*u + 3] * INV_C;
        *(float4*)&out[so + 4 * u] = w4;
    }
}

extern "C" void kernel_launch(void* const* d_in, const int* in_sizes, int n_in,
                              void* d_out, int out_size, void* d_ws, size_t ws_size,
                              hipStream_t stream) {
    const float* x  = (const float*)d_in[0];
    const float* Wk = (const float*)d_in[1];
    const float* Wv = (const float*)d_in[2];
    const float* Wq = (const float*)d_in[3];
    float* outp = (float*)d_out;

    const size_t MN = (size_t)T_DIM * B_DIM * N_DIM;
    float* kbuf = (float*)d_ws;
    float* vbuf = kbuf + MN;
    float* qbuf = vbuf + MN;

    proj_gemm<<<dim3(128, 8, 3), 256, 0, stream>>>(x, Wk, Wv, Wq, kbuf, vbuf, qbuf);
    knorm<<<2048, 256, 0, stream>>>(kbuf);
    scan_kernel<<<dim3(32, 16), 256, 0, stream>>>(kbuf, vbuf, qbuf, outp);
}

// Round 10
// 797.084 us; speedup vs baseline: 1.1942x; 1.1530x over previous
//
#include <hip/hip_runtime.h>
#include <hip/hip_bf16.h>

#define T_DIM 512
#define B_DIM 16
#define D_DIM 1024
#define N_DIM 512

// c-fold: store S' = C*S so the exp2 argument is a single fma.
// C = 2*log2(e); tanh via exp2: tanh(x) = 1 - 2/(exp2(C*x)+1)
#define C_FOLD  2.885390082f
#define INV_C   0.3465735903f

typedef short s16x8 __attribute__((ext_vector_type(8)));
typedef float f32x4 __attribute__((ext_vector_type(4)));
typedef float f32x2 __attribute__((ext_vector_type(2)));

__device__ __forceinline__ unsigned short f2bf(float f) {
    unsigned u = __float_as_uint(f);
    unsigned r = (u + 0x7fffu + ((u >> 16) & 1u)) >> 16;
    return (unsigned short)r;
}

// sum over the 32 lanes of this half-wave, result broadcast to all 32.
// (R3/R6-proven: 4 DPP adds + 1 ds_swizzle xor16.)
__device__ __forceinline__ float half32_sum(float x) {
    x += __int_as_float(__builtin_amdgcn_update_dpp(0, __float_as_int(x), 0xB1,  0xf, 0xf, true)); // quad_perm[1,0,3,2]
    x += __int_as_float(__builtin_amdgcn_update_dpp(0, __float_as_int(x), 0x4E,  0xf, 0xf, true)); // quad_perm[2,3,0,1]
    x += __int_as_float(__builtin_amdgcn_update_dpp(0, __float_as_int(x), 0x124, 0xf, 0xf, true)); // row_ror:4
    x += __int_as_float(__builtin_amdgcn_update_dpp(0, __float_as_int(x), 0x128, 0xf, 0xf, true)); // row_ror:8
    x += __int_as_float(__builtin_amdgcn_ds_swizzle(__float_as_int(x), 0x401F));                   // xor 16
    return x;
}

// pairwise tanh' on an f32x2 (S' domain): one rcp for two elements.
// w0 = 1/(e0+1) = (e1+1)*rcp((e0+1)(e1+1)); overflow of the product only
// happens when the partner term is >=2^38, where tanh==1 to 1e-11 anyway.
__device__ __forceinline__ f32x2 tanh2p(f32x2 arg, f32x2 Cv, f32x2 M2Cv) {
    float e0 = __builtin_amdgcn_exp2f(arg.x) + 1.0f;
    float e1 = __builtin_amdgcn_exp2f(arg.y) + 1.0f;
    float r  = __builtin_amdgcn_rcpf(e0 * e1);
    f32x2 w; w.x = e1 * r; w.y = e0 * r;
    return Cv + w * M2Cv;
}

// ---------------- projection GEMM: C[m,n] = sum_d x[m,d] * W[n,d] ----------
// v output pre-scaled by C_FOLD (scan works in S' = C*S domain).
__global__ __launch_bounds__(256) void proj_gemm(
    const float* __restrict__ x,
    const float* __restrict__ Wk,
    const float* __restrict__ Wv,
    const float* __restrict__ Wq,
    float* __restrict__ kbuf, float* __restrict__ vbuf, float* __restrict__ qbuf)
{
    const float* W = (blockIdx.z == 0) ? Wk : (blockIdx.z == 1) ? Wv : Wq;
    float* out = (blockIdx.z == 0) ? kbuf : (blockIdx.z == 1) ? vbuf : qbuf;
    const float oscale = (blockIdx.z == 1) ? C_FOLD : 1.0f;

    __shared__ __align__(16) unsigned short As[64 * 40];
    __shared__ __align__(16) unsigned short Bs[64 * 40];

    const int tid  = threadIdx.x;
    const int m0   = blockIdx.x * 64;
    const int n0   = blockIdx.y * 64;
    const int wave = tid >> 6;
    const int lane = tid & 63;
    const int l15  = lane & 15;
    const int quad = lane >> 4;

    const int srow = tid >> 2;
    const int scol = (tid & 3) * 8;

    f32x4 acc[4];
#pragma unroll
    for (int i = 0; i < 4; ++i) acc[i] = (f32x4)0.0f;

    for (int k0 = 0; k0 < D_DIM; k0 += 32) {
        __syncthreads();
        {
            const float* srcA = &x[(size_t)(m0 + srow) * D_DIM + k0 + scol];
            float4 a0 = *(const float4*)srcA;
            float4 a1 = *(const float4*)(srcA + 4);
            uint4 pa;
            pa.x = (unsigned)f2bf(a0.x) | ((unsigned)f2bf(a0.y) << 16);
            pa.y = (unsigned)f2bf(a0.z) | ((unsigned)f2bf(a0.w) << 16);
            pa.z = (unsigned)f2bf(a1.x) | ((unsigned)f2bf(a1.y) << 16);
            pa.w = (unsigned)f2bf(a1.z) | ((unsigned)f2bf(a1.w) << 16);
            *(uint4*)&As[srow * 40 + scol] = pa;

            const float* srcB = &W[(size_t)(n0 + srow) * D_DIM + k0 + scol];
            float4 b0 = *(const float4*)srcB;
            float4 b1 = *(const float4*)(srcB + 4);
            uint4 pb;
            pb.x = (unsigned)f2bf(b0.x) | ((unsigned)f2bf(b0.y) << 16);
            pb.y = (unsigned)f2bf(b0.z) | ((unsigned)f2bf(b0.w) << 16);
            pb.z = (unsigned)f2bf(b1.x) | ((unsigned)f2bf(b1.y) << 16);
            pb.w = (unsigned)f2bf(b1.z) | ((unsigned)f2bf(b1.w) << 16);
            *(uint4*)&Bs[srow * 40 + scol] = pb;
        }
        __syncthreads();
        s16x8 af = *(const s16x8*)&As[(wave * 16 + l15) * 40 + quad * 8];
#pragma unroll
        for (int nt = 0; nt < 4; ++nt) {
            s16x8 bf = *(const s16x8*)&Bs[(nt * 16 + l15) * 40 + quad * 8];
            acc[nt] = __builtin_amdgcn_mfma_f32_16x16x32_bf16(af, bf, acc[nt], 0, 0, 0);
        }
    }
#pragma unroll
    for (int nt = 0; nt < 4; ++nt) {
#pragma unroll
        for (int rg = 0; rg < 4; ++rg) {
            int row = m0 + wave * 16 + quad * 4 + rg;
            int col = n0 + nt * 16 + l15;
            out[(size_t)row * N_DIM + col] = acc[nt][rg] * oscale;
        }
    }
}

// ---------------- k row-normalization (in place) ---------------------------
__global__ __launch_bounds__(256) void knorm(float* __restrict__ kbuf)
{
    const int wave = threadIdx.x >> 6;
    const int lane = threadIdx.x & 63;
    const int row  = blockIdx.x * 4 + wave;
    float* p = &kbuf[(size_t)row * N_DIM + lane * 8];
    float4 a = *(const float4*)p;
    float4 b = *(const float4*)(p + 4);
    float s = a.x*a.x + a.y*a.y + a.z*a.z + a.w*a.w
            + b.x*b.x + b.y*b.y + b.z*b.z + b.w*b.w;
#pragma unroll
    for (int m = 1; m < 64; m <<= 1) s += __shfl_xor(s, m, 64);
    float inv = 1.0f / (sqrtf(s) + 1e-6f);
    a.x *= inv; a.y *= inv; a.z *= inv; a.w *= inv;
    b.x *= inv; b.y *= inv; b.z *= inv; b.w *= inv;
    *(float4*)p = a;
    *(float4*)(p + 4) = b;
}

// ---------------- sequential scan ------------------------------------------
// R6 structure (best measured: 706us): grid(32,16), block 256.
// Lane (wave wv, half h, tj=lane&31) owns TWO rows {4*wv+2*h, +1} x 16 cols
// [16*tj..16*tj+15] of S' (= C*S). Deltas vs R6: (a) stride-33 LDS chunks
// (R9-measured 0 bank conflicts): read base 33*(tj>>1)+16*(tj&1); (b) v
// pre-scaled by C in GEMM; (c) pairwise batched rcp in tanh (1 trans saved
// per 2 elements).
__global__ __launch_bounds__(256) void scan_kernel(
    const float* __restrict__ kbuf, const float* __restrict__ vbuf,
    const float* __restrict__ qbuf, float* __restrict__ out)
{
    __shared__ __align__(16) float ks[2][528];
    __shared__ __align__(16) float qs[2][528];
    __shared__ float vs[2][16];

    const int tid  = threadIdx.x;
    const int lane = tid & 63;
    const int wv   = tid >> 6;
    const int h    = lane >> 5;
    const int tj   = lane & 31;
    const int b    = blockIdx.y;
    const int i0   = blockIdx.x * 16;
    const int r0   = 4 * wv + 2 * h;   // local rows r0, r0+1

    // staging write: thread writes logical cols {2tid, 2tid+1} ->
    // chunk (2tid)>>5 (stride 33), offset (2tid)&31. b64, conflict-free.
    const int wA = 33 * (tid >> 4) + ((2 * tid) & 31);
    // read: lane tj covers cols [16tj..16tj+15] = chunk tj>>1, half tj&1
    const int rA = 33 * (tj >> 1) + 16 * (tj & 1);

    f32x2 SA[8], SB[8];
#pragma unroll
    for (int u = 0; u < 8; ++u) { SA[u] = (f32x2)0.0f; SB[u] = (f32x2)0.0f; }

    float2 pk, pq; float pv = 0.0f;
    {   // stage t=0 into buf0; prefetch t=1 into regs
        const size_t o0 = (size_t)b * N_DIM;
        pk = *(const float2*)&kbuf[o0 + 2 * tid];
        pq = *(const float2*)&qbuf[o0 + 2 * tid];
        if (tid < 16) pv = vbuf[o0 + i0 + tid];
        *(float2*)&ks[0][wA] = pk;
        *(float2*)&qs[0][wA] = pq;
        if (tid < 16) vs[0][tid] = pv;
        const size_t o1 = (size_t)(B_DIM + b) * N_DIM;
        pk = *(const float2*)&kbuf[o1 + 2 * tid];
        pq = *(const float2*)&qbuf[o1 + 2 * tid];
        if (tid < 16) pv = vbuf[o1 + i0 + tid];
    }
    __syncthreads();

    const f32x2 Cv   = {C_FOLD, C_FOLD};
    const f32x2 M2Cv = {-2.0f * C_FOLD, -2.0f * C_FOLD};

    for (int t = 0; t < T_DIM; ++t) {
        const int cb = t & 1, nb = cb ^ 1;
        const size_t ofs = ((size_t)t * B_DIM + b) * N_DIM;

        // stage t+1 (already in regs) into the other buffer
        if (t + 1 < T_DIM) {
            *(float2*)&ks[nb][wA] = pk;
            *(float2*)&qs[nb][wA] = pq;
            if (tid < 16) vs[nb][tid] = pv;
        }
        // issue global prefetch for t+2
        if (t + 2 < T_DIM) {
            const size_t o2 = ((size_t)(t + 2) * B_DIM + b) * N_DIM;
            pk = *(const float2*)&kbuf[o2 + 2 * tid];
            pq = *(const float2*)&qbuf[o2 + 2 * tid];
            if (tid < 16) pv = vbuf[o2 + i0 + tid];
        }

        f32x2 k2[8], q2[8];
#pragma unroll
        for (int u = 0; u < 4; ++u) {
            f32x4 kv = *(const f32x4*)&ks[cb][rA + 4 * u];
            f32x4 qv = *(const f32x4*)&qs[cb][rA + 4 * u];
            k2[2*u] = kv.xy; k2[2*u+1] = kv.zw;
            q2[2*u] = qv.xy; q2[2*u+1] = qv.zw;
        }
        const float v0 = vs[cb][r0];        // = C * v
        const float v1 = vs[cb][r0 + 1];

        // racc' = sum_j S'_ij k_j (2 partial accumulators per row)
        f32x2 pa0 = (f32x2)0.0f, pb0 = (f32x2)0.0f;
        f32x2 pa1 = (f32x2)0.0f, pb1 = (f32x2)0.0f;
#pragma unroll
        for (int u = 0; u < 8; u += 2) {
            pa0 += SA[u] * k2[u];  pb0 += SA[u + 1] * k2[u + 1];
            pa1 += SB[u] * k2[u];  pb1 += SB[u + 1] * k2[u + 1];
        }
        const float racc0 = half32_sum(pa0.x + pa0.y + pb0.x + pb0.y);
        const float racc1 = half32_sum(pa1.x + pa1.y + pb1.x + pb1.y);

        const float dp0 = v0 - racc0;       // dp' = C*v - racc'
        const float dp1 = v1 - racc1;
        const f32x2 d0 = {dp0, dp0}, d1 = {dp1, dp1};

        // S'_new = tanh' (pairwise rcp);  sq' += S'_new * q
        f32x2 sa0 = (f32x2)0.0f, sb0 = (f32x2)0.0f;
        f32x2 sa1 = (f32x2)0.0f, sb1 = (f32x2)0.0f;
#pragma unroll
        for (int u = 0; u < 8; u += 2) {
            f32x2 nA0 = tanh2p(SA[u]     + d0 * k2[u],     Cv, M2Cv);
            f32x2 nB0 = tanh2p(SB[u]     + d1 * k2[u],     Cv, M2Cv);
            f32x2 nA1 = tanh2p(SA[u + 1] + d0 * k2[u + 1], Cv, M2Cv);
            f32x2 nB1 = tanh2p(SB[u + 1] + d1 * k2[u + 1], Cv, M2Cv);
            SA[u] = nA0; SB[u] = nB0; SA[u + 1] = nA1; SB[u + 1] = nB1;
            sa0 += nA0 * q2[u];     sa1 += nB0 * q2[u];
            sb0 += nA1 * q2[u + 1]; sb1 += nB1 * q2[u + 1];
        }
        const float sq0 = half32_sum(sa0.x + sa0.y + sb0.x + sb0.y);
        const float sq1 = half32_sum(sa1.x + sa1.y + sb1.x + sb1.y);

        if (tj == 0) {
            float s0 = sq0 * INV_C, s1 = sq1 * INV_C;
            float g0 = __builtin_amdgcn_rcpf(1.0f + __builtin_amdgcn_exp2f(-s0 * 1.44269504f));
            float g1 = __builtin_amdgcn_rcpf(1.0f + __builtin_amdgcn_exp2f(-s1 * 1.44269504f));
            out[ofs + i0 + r0]     = s0 * s0 * g0;
            out[ofs + i0 + r0 + 1] = s1 * s1 * g1;
        }
        __syncthreads();
    }

    // S_final (true scale) -> d_out[T*B*N + ((b*N + i)*N + col)]
    const size_t base = (size_t)T_DIM * B_DIM * N_DIM;
    const size_t so0 = base + ((size_t)b * N_DIM + i0 + r0) * N_DIM + 16 * tj;
    const size_t so1 = so0 + N_DIM;
#pragma unroll
    for (int u = 0; u < 4; ++u) {
        float4 w0, w1;
        w0.x = SA[2*u].x   * INV_C; w0.y = SA[2*u].y   * INV_C;
        w0.z = SA[2*u+1].x * INV_C; w0.w = SA[2*u+1].y * INV_C;
        w1.x = SB[2*u].x   * INV_C; w1.y = SB[2*u].y   * INV_C;
        w1.z = SB[2*u+1].x * INV_C; w1.w = SB[2*u+1].y * INV_C;
        *(float4*)&out[so0 + 4 * u] = w0;
        *(float4*)&out[so1 + 4 * u] = w1;
    }
}

extern "C" void kernel_launch(void* const* d_in, const int* in_sizes, int n_in,
                              void* d_out, int out_size, void* d_ws, size_t ws_size,
                              hipStream_t stream) {
    const float* x  = (const float*)d_in[0];
    const float* Wk = (const float*)d_in[1];
    const float* Wv = (const float*)d_in[2];
    const float* Wq = (const float*)d_in[3];
    float* outp = (float*)d_out;

    const size_t MN = (size_t)T_DIM * B_DIM * N_DIM;
    float* kbuf = (float*)d_ws;
    float* vbuf = kbuf + MN;
    float* qbuf = vbuf + MN;

    proj_gemm<<<dim3(128, 8, 3), 256, 0, stream>>>(x, Wk, Wv, Wq, kbuf, vbuf, qbuf);
    knorm<<<2048, 256, 0, stream>>>(kbuf);
    scan_kernel<<<dim3(32, 16), 256, 0, stream>>>(kbuf, vbuf, qbuf, outp);
}